// Round 10
// baseline (120.727 us; speedup 1.0000x reference)
//
#include <hip/hip_runtime.h>
#include <hip/hip_bf16.h>

#define TT 512
#define BB 64
#define KK 10
#define DD 1024
#define CL 32   // chunk length (steps per chunk)
#define NC 16   // number of chunks

typedef unsigned char uchar;
typedef short bf16x8 __attribute__((ext_vector_type(8)));
typedef float f32x4 __attribute__((ext_vector_type(4)));

__device__ __forceinline__ unsigned f2bf(float f) {  // RNE f32 -> bf16 bits
    unsigned u = __float_as_uint(f);
    return (u + 0x7FFFu + ((u >> 16) & 1u)) >> 16;
}

__device__ __forceinline__ float max10(const float* r) {
    float m0 = fmaxf(r[0], r[1]), m1 = fmaxf(r[2], r[3]);
    float m2 = fmaxf(r[4], r[5]), m3 = fmaxf(r[6], r[7]);
    float m4 = fmaxf(r[8], r[9]);
    m0 = fmaxf(m0, m1); m2 = fmaxf(m2, m3); m0 = fmaxf(m0, m2);
    return fmaxf(m0, m4);
}

__device__ __forceinline__ float lse10(const float* r) {
    const float m = max10(r);
    float s0 = __expf(r[0] - m) + __expf(r[1] - m);
    float s1 = __expf(r[2] - m) + __expf(r[3] - m);
    float s2 = __expf(r[4] - m) + __expf(r[5] - m);
    float s3 = __expf(r[6] - m) + __expf(r[7] - m);
    float s4 = __expf(r[8] - m) + __expf(r[9] - m);
    return m + __logf(((s0 + s1) + (s2 + s3)) + s4);
}

// ---------------- Kernel A1: pure-stream convert f32 -> bf16 fragments ------
// 2048 blocks x 256 thr, 8 grid-stride iters; per iter: 2 linear float4 loads,
// RNE pack, one uint4 store into A-fragment tile layout [tile][ks][kg][arow].
// No LDS / barriers / dependent compute: the m13 streaming shape.
// Block 2048: lengths + loss init + B-fragment table build.
__global__ __launch_bounds__(256) void k_convert(
    const int* __restrict__ words, const float* __restrict__ wf,
    const float* __restrict__ W, uint4* __restrict__ frag,
    int* __restrict__ lenArr, float* loss_slot, uint4* __restrict__ Bfg) {
    const int tid = threadIdx.x;
    if (blockIdx.x == 2048) {
        __shared__ int cnt[4][64];
        const int b = tid & 63, seg = tid >> 6;
        int c = 0;
        for (int t = seg; t < TT; t += 4) c += (words[t * BB + b] != 0) ? 1 : 0;
        cnt[seg][b] = c;
        __syncthreads();
        if (tid < 64)
            lenArr[tid] = cnt[0][tid] + cnt[1][tid] + cnt[2][tid] + cnt[3][tid];
        if (tid == 0) *loss_slot = 0.f;
        // compact B-fragment table: Bfg[ks*40 + kg*10 + col]
        for (int idx = tid; idx < 32 * 40; idx += 256) {
            const int ks = idx / 40, rem = idx - ks * 40;
            const int kg = rem / 10, col = rem - kg * 10;
            unsigned u[4];
            #pragma unroll
            for (int p = 0; p < 4; ++p) {
                const int k0 = ks * 32 + kg * 8 + p * 2;
                u[p] = f2bf(W[(size_t)k0 * KK + col]) |
                       (f2bf(W[(size_t)(k0 + 1) * KK + col]) << 16);
            }
            Bfg[idx] = make_uint4(u[0], u[1], u[2], u[3]);
        }
        return;
    }
    const int t0 = blockIdx.x * 256 + tid;
    #pragma unroll
    for (int i = 0; i < 8; ++i) {
        const int tt = i * 524288 + t0;          // thread-chunk index (32 B each)
        const size_t e = (size_t)tt * 8;         // element index (8 floats)
        const float4 f0 = *reinterpret_cast<const float4*>(wf + e);
        const float4 f1 = *reinterpret_cast<const float4*>(wf + e + 4);
        uint4 o;
        o.x = f2bf(f0.x) | (f2bf(f0.y) << 16);
        o.y = f2bf(f0.z) | (f2bf(f0.w) << 16);
        o.z = f2bf(f1.x) | (f2bf(f1.y) << 16);
        o.w = f2bf(f1.z) | (f2bf(f1.w) << 16);
        const int r = tt >> 7, dblk = tt & 127;  // row, 8-elem block within row
        const int tile = r >> 4, arow = r & 15;
        const int ks = dblk >> 2, kg = dblk & 3;
        frag[(size_t)tile * 2048 + ks * 64 + kg * 16 + arow] = o;
    }
}

// ---------------- Kernel A2: linear-read MFMA emissions ---------------------
// 2048 blocks x 256 thr; block = one 16-row tile, wave = K quarter (8 ks).
// Wave loads are lane-linear 1-KB uint4 reads from the fragment buffer;
// all 8 issued upfront (8 KB/wave in flight), then 8 MFMAs; LDS reduce.
__global__ __launch_bounds__(256) void k_mfma(
    const uint4* __restrict__ frag, const uint4* __restrict__ Bfg,
    const float* __restrict__ bias, float* __restrict__ em) {
    __shared__ f32x4 red[256];
    const int tid = threadIdx.x;
    const int wv = tid >> 6, lane = tid & 63;
    const int arow = lane & 15, kg = lane >> 4;
    const int tile = blockIdx.x;

    const uint4* src = frag + (size_t)tile * 2048 + wv * 8 * 64 + lane;
    bf16x8 a[8];
    #pragma unroll
    for (int q = 0; q < 8; ++q) {
        union { uint4 u; bf16x8 v; } tu; tu.u = src[q * 64]; a[q] = tu.v;
    }
    const int bcol = kg * 10 + (arow < KK ? arow : KK - 1);  // junk col for lanes >=10 (unwritten)
    bf16x8 bq[8];
    #pragma unroll
    for (int q = 0; q < 8; ++q) {
        union { uint4 u; bf16x8 v; } tu; tu.u = Bfg[(wv * 8 + q) * 40 + bcol]; bq[q] = tu.v;
    }
    f32x4 acc = {0.f, 0.f, 0.f, 0.f};
    #pragma unroll
    for (int q = 0; q < 8; ++q)
        acc = __builtin_amdgcn_mfma_f32_16x16x32_bf16(a[q], bq[q], acc, 0, 0, 0);

    red[tid] = acc;
    __syncthreads();
    if (wv == 0 && arow < KK) {
        f32x4 s = red[lane];
        #pragma unroll
        for (int w = 1; w < 4; ++w) {
            const f32x4 p = red[w * 64 + lane];
            s[0] += p[0]; s[1] += p[1]; s[2] += p[2]; s[3] += p[3];
        }
        const float bk = bias[arow];
        const int row0 = tile * 16;
        // C layout: col = lane&15, row = (lane>>4)*4 + reg  [m89]
        #pragma unroll
        for (int r = 0; r < 4; ++r)
            em[(size_t)(row0 + kg * 4 + r) * KK + arow] = s[r] + bk;
    }
}

// ---------------- Kernel B: per-chunk 10x10 transfer matrices ---------------
// grid 2048: blockIdx = sem*1024 + b*16 + c; 128 threads, (i,j) = tid/10,tid%10.
__global__ __launch_bounds__(128) void k_chunk(
    const float* __restrict__ em, const float* __restrict__ trans,
    const int* __restrict__ lenArr, float* __restrict__ Mlse, float* __restrict__ Mmax) {
    int id = blockIdx.x;
    const bool mx = id >= 1024; id &= 1023;
    const int b = id >> 4, c = id & 15;
    const int len = lenArr[b];
    const int s_lo = c * CL + 1;
    const int s_hi = min(c * CL + CL, len - 1);
    const int ns = s_hi - s_lo + 1;
    if (ns <= 0) return;  // identity chunk: consumers skip it

    __shared__ float Ms[KK][12];
    __shared__ float eml[CL][KK];
    const int tid = threadIdx.x;
    for (int idx = tid; idx < CL * KK; idx += 128) {
        const int sl = idx / KK, j = idx % KK;
        const int s = s_lo + sl;
        eml[sl][j] = (s <= TT - 1) ? em[((size_t)s * BB + b) * KK + j] : 0.f;
    }
    const int i = tid / KK, j = tid % KK;
    const bool act = tid < KK * KK;
    float trc[KK];
    if (act) {
        #pragma unroll
        for (int k = 0; k < KK; ++k) trc[k] = trans[k * KK + j];
    }
    __syncthreads();
    float cur = 0.f;
    if (act) { cur = trans[i * KK + j] + eml[0][j]; Ms[i][j] = cur; }
    __syncthreads();
    for (int sl = 1; sl < ns; ++sl) {
        float row[KK];
        if (act) {
            #pragma unroll
            for (int k = 0; k < KK; ++k) row[k] = Ms[i][k] + trc[k];
        }
        __syncthreads();
        if (act) {
            cur = (mx ? max10(row) : lse10(row)) + eml[sl][j];
            Ms[i][j] = cur;
        }
        __syncthreads();
    }
    if (act) {
        float* out = mx ? Mmax : Mlse;
        out[((size_t)b * NC + c) * 100 + i * KK + j] = cur;
    }
}

// ---------------- Kernel C: merged fold + hist + backtrace + loss -----------
// grid 64 (one block per batch) x 1024 threads (16 waves).
__global__ __launch_bounds__(1024) void k_crf(
    const int* __restrict__ tags, const float* __restrict__ em,
    const float* __restrict__ startv, const float* __restrict__ endv,
    const float* __restrict__ trans, const int* __restrict__ lenArr,
    const float* __restrict__ Mlse, const float* __restrict__ Mmax,
    int* __restrict__ paths, float* __restrict__ loss_slot) {
    const int b = blockIdx.x;
    const int tid = threadIdx.x;
    const int wv = tid >> 6, lane = tid & 63;
    const int len = lenArr[b];

    __shared__ float Ml[NC][100];
    __shared__ float Mm[NC][100];
    __shared__ float eml[NC][CL][KK];
    __shared__ float ub[NC][KK];
    __shared__ uchar hl[NC][CL * KK];
    __shared__ int   Fl[NC][KK];
    __shared__ int   vt[NC + 1];
    __shared__ float em0[KK];
    __shared__ float red[2];

    for (int idx = tid; idx < NC * 100; idx += 1024) {
        Ml[idx / 100][idx % 100] = Mlse[(size_t)b * NC * 100 + idx];
        Mm[idx / 100][idx % 100] = Mmax[(size_t)b * NC * 100 + idx];
    }
    for (int idx = tid; idx < NC * CL * KK; idx += 1024) {
        const int c = idx / (CL * KK), r = idx % (CL * KK);
        const int sl = r / KK, j = r % KK;
        const int s = c * CL + 1 + sl;
        eml[c][sl][j] = (s <= TT - 1) ? em[((size_t)s * BB + b) * KK + j] : 0.f;
    }
    if (tid < KK) em0[tid] = em[(size_t)b * KK + tid];
    __syncthreads();

    if (wv == 0) {  // max-plus fold -> boundary vectors + last tag
        float v[KK];
        #pragma unroll
        for (int i = 0; i < KK; ++i) v[i] = startv[i] + em0[i];
        for (int c = 0; c < NC; ++c) {
            if (lane < KK) ub[c][lane] = v[lane];
            const int s_hi = min(c * CL + CL, len - 1);
            if (s_hi >= c * CL + 1) {
                float nv = 0.f;
                if (lane < KK) {
                    float r[KK];
                    #pragma unroll
                    for (int k = 0; k < KK; ++k) r[k] = v[k] + Mm[c][k * KK + lane];
                    nv = max10(r);
                }
                #pragma unroll
                for (int i = 0; i < KK; ++i) v[i] = __shfl(nv, i);
            }
        }
        float best = v[0] + endv[0];
        int bi = 0;
        #pragma unroll
        for (int i = 1; i < KK; ++i) {
            const float x = v[i] + endv[i];
            if (x > best) { best = x; bi = i; }
        }
        if (lane == 0) vt[NC] = bi;
    } else if (wv == 1) {  // LSE fold -> denominator
        float v[KK];
        #pragma unroll
        for (int i = 0; i < KK; ++i) v[i] = startv[i] + em0[i];
        for (int c = 0; c < NC; ++c) {
            const int s_hi = min(c * CL + CL, len - 1);
            if (s_hi >= c * CL + 1) {
                float nv = 0.f;
                if (lane < KK) {
                    float r[KK];
                    #pragma unroll
                    for (int k = 0; k < KK; ++k) r[k] = v[k] + Ml[c][k * KK + lane];
                    nv = lse10(r);
                }
                #pragma unroll
                for (int i = 0; i < KK; ++i) v[i] = __shfl(nv, i);
            }
        }
        float r[KK];
        #pragma unroll
        for (int i = 0; i < KK; ++i) r[i] = v[i] + endv[i];
        if (lane == 0) red[0] = lse10(r);
    } else if (wv == 2) {  // gold-path numerator
        float part = 0.f;
        for (int t = 1 + lane; t < len; t += 64) {
            const int tp = tags[(t - 1) * BB + b];
            const int tc = tags[t * BB + b];
            part += trans[tp * KK + tc] + eml[(t - 1) >> 5][(t - 1) & 31][tc];
        }
        #pragma unroll
        for (int off = 32; off >= 1; off >>= 1) part += __shfl_xor(part, off);
        if (lane == 0) {
            const int t0 = tags[b];
            const int te = tags[(len - 1) * BB + b];
            red[1] = part + startv[t0] + em0[t0] + endv[te];
        }
    }
    __syncthreads();

    // per-chunk Viterbi re-run from exact boundary vector (wave c owns chunk c)
    {
        const int c = wv;
        const int s_hi = min(c * CL + CL, len - 1);
        const int ns = s_hi - (c * CL + 1) + 1;
        if (ns > 0) {
            float trc[KK];
            if (lane < KK) {
                #pragma unroll
                for (int i = 0; i < KK; ++i) trc[i] = trans[i * KK + lane];
            }
            float s[KK];
            #pragma unroll
            for (int i = 0; i < KK; ++i) s[i] = ub[c][i];
            for (int sl = 0; sl < ns; ++sl) {
                float best = s[0] + trc[0];
                int bi = 0;
                #pragma unroll
                for (int i = 1; i < KK; ++i) {
                    const float x = s[i] + trc[i];
                    if (x > best) { best = x; bi = i; }
                }
                float snew = 0.f;
                if (lane < KK) {
                    snew = best + eml[c][sl][lane];
                    hl[c][sl * KK + lane] = (uchar)bi;
                }
                #pragma unroll
                for (int i = 0; i < KK; ++i) s[i] = __shfl(snew, i);
            }
            if (lane < KK) {
                int cur = lane;
                for (int sl = ns - 1; sl >= 0; --sl) cur = hl[c][sl * KK + cur];
                Fl[c][lane] = cur;
            }
        }
    }
    __syncthreads();

    if (tid == 0) {  // boundary-tag fold + loss
        int cur = vt[NC];
        for (int c = NC - 1; c >= 0; --c) {
            const int s_hi = min(c * CL + CL, len - 1);
            if (s_hi >= c * CL + 1) cur = Fl[c][cur];
            vt[c] = cur;
        }
        atomicAdd(loss_slot, red[0] - red[1]);
    }
    __syncthreads();

    // emit: wave w writes path slice [32w, 32w+31]
    const int t0 = wv * CL;
    if (lane < CL) {
        const int t = t0 + lane;
        if (t >= len) paths[t * BB + b] = 0;
    }
    if (lane == 0) {
        const int a = min(t0 + CL, len - 1);
        if (a >= t0) {
            int cur = vt[wv + 1];  // = path[a]
            for (int t = a; t >= t0; --t) {
                if (t <= t0 + CL - 1) paths[t * BB + b] = cur;
                if (t > t0) cur = (int)hl[wv][(t - t0 - 1) * KK + cur];
            }
        }
    }
}

extern "C" void kernel_launch(void* const* d_in, const int* in_sizes, int n_in,
                              void* d_out, int out_size, void* d_ws, size_t ws_size,
                              hipStream_t stream) {
    const int*   words  = (const int*)d_in[0];
    const int*   tags   = (const int*)d_in[1];
    const float* wf     = (const float*)d_in[2];
    const float* W      = (const float*)d_in[3];
    const float* bias   = (const float*)d_in[4];
    const float* startv = (const float*)d_in[5];
    const float* endv   = (const float*)d_in[6];
    const float* trans  = (const float*)d_in[7];

    // workspace layout (bytes)
    uchar* base = (uchar*)d_ws;
    uint4* frag = (uint4*)base;                         // 67,108,864 B bf16 fragments
    float* em   = (float*)(base + 67108864);            // 1,310,720 B
    float* Mlse = (float*)(base + 68419584);            // 409,600 B
    float* Mmax = (float*)(base + 68829184);            // 409,600 B
    int*   lenA = (int*)  (base + 69238784);            // 256 B
    uint4* Bfg  = (uint4*)(base + 69239040);            // 20,480 B

    int*   paths     = (int*)d_out;                     // (T,B) int32 values
    float* loss_slot = ((float*)d_out) + TT * BB;       // scalar f32

    k_convert<<<2049, 256, 0, stream>>>(words, wf, W, frag, lenA, loss_slot, Bfg);
    k_mfma<<<2048, 256, 0, stream>>>(frag, Bfg, bias, em);
    k_chunk<<<2048, 128, 0, stream>>>(em, trans, lenA, Mlse, Mmax);
    k_crf<<<64, 1024, 0, stream>>>(tags, em, startv, endv, trans, lenA,
                                   Mlse, Mmax, paths, loss_slot);
}

// Round 11
// 80.228 us; speedup vs baseline: 1.5048x; 1.5048x over previous
//
#include <hip/hip_runtime.h>
#include <hip/hip_bf16.h>

#define TT 512
#define BB 64
#define KK 10
#define DD 1024
#define CL 32   // chunk length (steps per chunk)
#define NC 16   // number of chunks

typedef unsigned char uchar;
typedef short bf16x8 __attribute__((ext_vector_type(8)));
typedef float f32x4 __attribute__((ext_vector_type(4)));

__device__ __forceinline__ unsigned f2bf(float f) {  // RNE f32 -> bf16 bits
    unsigned u = __float_as_uint(f);
    return (u + 0x7FFFu + ((u >> 16) & 1u)) >> 16;
}

__device__ __forceinline__ float max10(const float* r) {
    float m0 = fmaxf(r[0], r[1]), m1 = fmaxf(r[2], r[3]);
    float m2 = fmaxf(r[4], r[5]), m3 = fmaxf(r[6], r[7]);
    float m4 = fmaxf(r[8], r[9]);
    m0 = fmaxf(m0, m1); m2 = fmaxf(m2, m3); m0 = fmaxf(m0, m2);
    return fmaxf(m0, m4);
}

__device__ __forceinline__ float lse10(const float* r) {
    const float m = max10(r);
    float s0 = __expf(r[0] - m) + __expf(r[1] - m);
    float s1 = __expf(r[2] - m) + __expf(r[3] - m);
    float s2 = __expf(r[4] - m) + __expf(r[5] - m);
    float s3 = __expf(r[6] - m) + __expf(r[7] - m);
    float s4 = __expf(r[8] - m) + __expf(r[9] - m);
    return m + __logf(((s0 + s1) + (s2 + s3)) + s4);
}

// ---------------- Kernel A: emissions via MFMA + lengths (R6 champion) ------
// blocks 0..255: 128 rows (8 waves x one 16x16 tile, K=1024). B-fragments
// register-resident (phase double-buffered from LDS); A direct per-lane gather
// with 4-deep ring prefetch — empirically the fastest wf-read structure.
// block 256: lengths per batch + zero loss slot.
__global__ __launch_bounds__(512) void k_emissions(
    const int* __restrict__ words, const float* __restrict__ wf,
    const float* __restrict__ W, const float* __restrict__ bias,
    float* __restrict__ em, int* __restrict__ lenArr, float* loss_slot) {
    const int tid = threadIdx.x;
    if (blockIdx.x == 256) {
        __shared__ int cnt[8][64];
        const int b = tid & 63, seg = tid >> 6;
        int c = 0;
        for (int t = seg; t < TT; t += 8) c += (words[t * BB + b] != 0) ? 1 : 0;
        cnt[seg][b] = c;
        __syncthreads();
        if (tid < 64) {
            int s = 0;
            #pragma unroll
            for (int g = 0; g < 8; ++g) s += cnt[g][tid];
            lenArr[tid] = s;
        }
        if (tid == 0) *loss_slot = 0.f;
        return;
    }

    // B-fragment table: Bfrag[ks][lane] = 8 bf16 of W[ks*32 + (lane>>4)*8 + p][lane&15]
    __shared__ uint4 Bfrag[32][64];  // 32 KB
    for (int idx = tid; idx < 32 * 64; idx += 512) {
        const int ks = idx >> 6, l = idx & 63;
        const int col = l & 15, kg2 = l >> 4;
        unsigned u[4];
        #pragma unroll
        for (int p = 0; p < 4; ++p) {
            unsigned lo = 0, hi = 0;
            if (col < KK) {
                const int k0 = ks * 32 + kg2 * 8 + p * 2;
                lo = f2bf(W[(size_t)k0 * KK + col]);
                hi = f2bf(W[(size_t)(k0 + 1) * KK + col]);
            }
            u[p] = lo | (hi << 16);
        }
        Bfrag[ks][l] = make_uint4(u[0], u[1], u[2], u[3]);
    }
    __syncthreads();

    const int wave = tid >> 6, lane = tid & 63;
    const int arow = lane & 15;      // A row within tile (== C col)
    const int kg   = lane >> 4;      // k-group (and C row-group)
    const int row0 = blockIdx.x * 128 + wave * 16;
    const float* ap = wf + (size_t)(row0 + arow) * DD + kg * 8;
    const float bk = bias[arow < KK ? arow : 0];

    f32x4 acc = {0.f, 0.f, 0.f, 0.f};
    float4 fa[4], fb[4];
    #pragma unroll
    for (int p = 0; p < 4; ++p) {
        fa[p] = *reinterpret_cast<const float4*>(ap + p * 32);
        fb[p] = *reinterpret_cast<const float4*>(ap + p * 32 + 4);
    }
    uint4 bcur[8], bnxt[8];
    #pragma unroll
    for (int q = 0; q < 8; ++q) bcur[q] = Bfrag[q][lane];

    #pragma unroll
    for (int ph = 0; ph < 4; ++ph) {
        if (ph < 3) {
            #pragma unroll
            for (int q = 0; q < 8; ++q) bnxt[q] = Bfrag[(ph + 1) * 8 + q][lane];
        }
        #pragma unroll
        for (int q = 0; q < 8; ++q) {
            const int ks = ph * 8 + q;
            const int s = ks & 3;
            bf16x8 afr;
            afr[0] = (short)f2bf(fa[s].x); afr[1] = (short)f2bf(fa[s].y);
            afr[2] = (short)f2bf(fa[s].z); afr[3] = (short)f2bf(fa[s].w);
            afr[4] = (short)f2bf(fb[s].x); afr[5] = (short)f2bf(fb[s].y);
            afr[6] = (short)f2bf(fb[s].z); afr[7] = (short)f2bf(fb[s].w);
            if (ks < 28) {  // keep ~6-8 KB/wave in flight
                fa[s] = *reinterpret_cast<const float4*>(ap + (ks + 4) * 32);
                fb[s] = *reinterpret_cast<const float4*>(ap + (ks + 4) * 32 + 4);
            }
            union { uint4 u; bf16x8 v; } bu;
            bu.u = bcur[q];
            acc = __builtin_amdgcn_mfma_f32_16x16x32_bf16(afr, bu.v, acc, 0, 0, 0);
        }
        #pragma unroll
        for (int q = 0; q < 8; ++q) bcur[q] = bnxt[q];
    }
    // C layout: col = lane&15, row = (lane>>4)*4 + reg  [m89]
    if (arow < KK) {
        #pragma unroll
        for (int r = 0; r < 4; ++r)
            em[(size_t)(row0 + kg * 4 + r) * KK + arow] = acc[r] + bk;
    }
}

// ---------------- Kernel B: per-chunk transfer matrices, BOTH semirings -----
// grid 1024: blockIdx = b*16 + c; 128 threads, (i,j) = tid/10, tid%10.
// One pass computes the LSE and max-plus chunk matrices together (shared eml
// staging + shared syncs; VALU per step doubles but the loop is sync-bound).
__global__ __launch_bounds__(128) void k_chunk(
    const float* __restrict__ em, const float* __restrict__ trans,
    const int* __restrict__ lenArr, float* __restrict__ Mlse, float* __restrict__ Mmax) {
    const int b = blockIdx.x >> 4, c = blockIdx.x & 15;
    const int len = lenArr[b];
    const int s_lo = c * CL + 1;
    const int s_hi = min(c * CL + CL, len - 1);
    const int ns = s_hi - s_lo + 1;
    if (ns <= 0) return;  // identity chunk: consumers skip it

    __shared__ float MsL[KK][12];
    __shared__ float MsM[KK][12];
    __shared__ float eml[CL][KK];
    const int tid = threadIdx.x;
    for (int idx = tid; idx < CL * KK; idx += 128) {
        const int sl = idx / KK, j = idx % KK;
        const int s = s_lo + sl;
        eml[sl][j] = (s <= TT - 1) ? em[((size_t)s * BB + b) * KK + j] : 0.f;
    }
    const int i = tid / KK, j = tid % KK;
    const bool act = tid < KK * KK;
    float trc[KK];
    if (act) {
        #pragma unroll
        for (int k = 0; k < KK; ++k) trc[k] = trans[k * KK + j];
    }
    __syncthreads();
    float curL = 0.f, curM = 0.f;
    if (act) {
        curL = curM = trans[i * KK + j] + eml[0][j];
        MsL[i][j] = curL; MsM[i][j] = curM;
    }
    __syncthreads();
    for (int sl = 1; sl < ns; ++sl) {
        float rowL[KK], rowM[KK];
        if (act) {
            #pragma unroll
            for (int k = 0; k < KK; ++k) {
                rowL[k] = MsL[i][k] + trc[k];
                rowM[k] = MsM[i][k] + trc[k];
            }
        }
        __syncthreads();
        if (act) {
            curL = lse10(rowL) + eml[sl][j];
            curM = max10(rowM) + eml[sl][j];
            MsL[i][j] = curL; MsM[i][j] = curM;
        }
        __syncthreads();
    }
    if (act) {
        Mlse[((size_t)b * NC + c) * 100 + i * KK + j] = curL;
        Mmax[((size_t)b * NC + c) * 100 + i * KK + j] = curM;
    }
}

// ---------------- Kernel C: merged fold + hist + backtrace + loss -----------
// grid 64 (one block per batch) x 1024 threads (16 waves).
__global__ __launch_bounds__(1024) void k_crf(
    const int* __restrict__ tags, const float* __restrict__ em,
    const float* __restrict__ startv, const float* __restrict__ endv,
    const float* __restrict__ trans, const int* __restrict__ lenArr,
    const float* __restrict__ Mlse, const float* __restrict__ Mmax,
    int* __restrict__ paths, float* __restrict__ loss_slot) {
    const int b = blockIdx.x;
    const int tid = threadIdx.x;
    const int wv = tid >> 6, lane = tid & 63;
    const int len = lenArr[b];

    __shared__ float Ml[NC][100];
    __shared__ float Mm[NC][100];
    __shared__ float eml[NC][CL][KK];
    __shared__ float ub[NC][KK];
    __shared__ uchar hl[NC][CL * KK];
    __shared__ int   Fl[NC][KK];
    __shared__ int   vt[NC + 1];
    __shared__ float em0[KK];
    __shared__ float red[2];

    for (int idx = tid; idx < NC * 100; idx += 1024) {
        Ml[idx / 100][idx % 100] = Mlse[(size_t)b * NC * 100 + idx];
        Mm[idx / 100][idx % 100] = Mmax[(size_t)b * NC * 100 + idx];
    }
    for (int idx = tid; idx < NC * CL * KK; idx += 1024) {
        const int c = idx / (CL * KK), r = idx % (CL * KK);
        const int sl = r / KK, j = r % KK;
        const int s = c * CL + 1 + sl;
        eml[c][sl][j] = (s <= TT - 1) ? em[((size_t)s * BB + b) * KK + j] : 0.f;
    }
    if (tid < KK) em0[tid] = em[(size_t)b * KK + tid];
    __syncthreads();

    if (wv == 0) {  // max-plus fold -> boundary vectors + last tag
        float v[KK];
        #pragma unroll
        for (int i = 0; i < KK; ++i) v[i] = startv[i] + em0[i];
        for (int c = 0; c < NC; ++c) {
            if (lane < KK) ub[c][lane] = v[lane];
            const int s_hi = min(c * CL + CL, len - 1);
            if (s_hi >= c * CL + 1) {
                float nv = 0.f;
                if (lane < KK) {
                    float r[KK];
                    #pragma unroll
                    for (int k = 0; k < KK; ++k) r[k] = v[k] + Mm[c][k * KK + lane];
                    nv = max10(r);
                }
                #pragma unroll
                for (int i = 0; i < KK; ++i) v[i] = __shfl(nv, i);
            }
        }
        float best = v[0] + endv[0];
        int bi = 0;
        #pragma unroll
        for (int i = 1; i < KK; ++i) {
            const float x = v[i] + endv[i];
            if (x > best) { best = x; bi = i; }
        }
        if (lane == 0) vt[NC] = bi;
    } else if (wv == 1) {  // LSE fold -> denominator
        float v[KK];
        #pragma unroll
        for (int i = 0; i < KK; ++i) v[i] = startv[i] + em0[i];
        for (int c = 0; c < NC; ++c) {
            const int s_hi = min(c * CL + CL, len - 1);
            if (s_hi >= c * CL + 1) {
                float nv = 0.f;
                if (lane < KK) {
                    float r[KK];
                    #pragma unroll
                    for (int k = 0; k < KK; ++k) r[k] = v[k] + Ml[c][k * KK + lane];
                    nv = lse10(r);
                }
                #pragma unroll
                for (int i = 0; i < KK; ++i) v[i] = __shfl(nv, i);
            }
        }
        float r[KK];
        #pragma unroll
        for (int i = 0; i < KK; ++i) r[i] = v[i] + endv[i];
        if (lane == 0) red[0] = lse10(r);
    } else if (wv == 2) {  // gold-path numerator
        float part = 0.f;
        for (int t = 1 + lane; t < len; t += 64) {
            const int tp = tags[(t - 1) * BB + b];
            const int tc = tags[t * BB + b];
            part += trans[tp * KK + tc] + eml[(t - 1) >> 5][(t - 1) & 31][tc];
        }
        #pragma unroll
        for (int off = 32; off >= 1; off >>= 1) part += __shfl_xor(part, off);
        if (lane == 0) {
            const int t0 = tags[b];
            const int te = tags[(len - 1) * BB + b];
            red[1] = part + startv[t0] + em0[t0] + endv[te];
        }
    }
    __syncthreads();

    // per-chunk Viterbi re-run from exact boundary vector (wave c owns chunk c)
    {
        const int c = wv;
        const int s_hi = min(c * CL + CL, len - 1);
        const int ns = s_hi - (c * CL + 1) + 1;
        if (ns > 0) {
            float trc[KK];
            if (lane < KK) {
                #pragma unroll
                for (int i = 0; i < KK; ++i) trc[i] = trans[i * KK + lane];
            }
            float s[KK];
            #pragma unroll
            for (int i = 0; i < KK; ++i) s[i] = ub[c][i];
            for (int sl = 0; sl < ns; ++sl) {
                float best = s[0] + trc[0];
                int bi = 0;
                #pragma unroll
                for (int i = 1; i < KK; ++i) {
                    const float x = s[i] + trc[i];
                    if (x > best) { best = x; bi = i; }
                }
                float snew = 0.f;
                if (lane < KK) {
                    snew = best + eml[c][sl][lane];
                    hl[c][sl * KK + lane] = (uchar)bi;
                }
                #pragma unroll
                for (int i = 0; i < KK; ++i) s[i] = __shfl(snew, i);
            }
            if (lane < KK) {
                int cur = lane;
                for (int sl = ns - 1; sl >= 0; --sl) cur = hl[c][sl * KK + cur];
                Fl[c][lane] = cur;
            }
        }
    }
    __syncthreads();

    if (tid == 0) {  // boundary-tag fold + loss
        int cur = vt[NC];
        for (int c = NC - 1; c >= 0; --c) {
            const int s_hi = min(c * CL + CL, len - 1);
            if (s_hi >= c * CL + 1) cur = Fl[c][cur];
            vt[c] = cur;
        }
        atomicAdd(loss_slot, red[0] - red[1]);
    }
    __syncthreads();

    // emit: wave w writes path slice [32w, 32w+31]
    const int t0 = wv * CL;
    if (lane < CL) {
        const int t = t0 + lane;
        if (t >= len) paths[t * BB + b] = 0;
    }
    if (lane == 0) {
        const int a = min(t0 + CL, len - 1);
        if (a >= t0) {
            int cur = vt[wv + 1];  // = path[a]
            for (int t = a; t >= t0; --t) {
                if (t <= t0 + CL - 1) paths[t * BB + b] = cur;
                if (t > t0) cur = (int)hl[wv][(t - t0 - 1) * KK + cur];
            }
        }
    }
}

extern "C" void kernel_launch(void* const* d_in, const int* in_sizes, int n_in,
                              void* d_out, int out_size, void* d_ws, size_t ws_size,
                              hipStream_t stream) {
    const int*   words  = (const int*)d_in[0];
    const int*   tags   = (const int*)d_in[1];
    const float* wf     = (const float*)d_in[2];
    const float* W      = (const float*)d_in[3];
    const float* bias   = (const float*)d_in[4];
    const float* startv = (const float*)d_in[5];
    const float* endv   = (const float*)d_in[6];
    const float* trans  = (const float*)d_in[7];

    float* em   = (float*)d_ws;                       // 512*64*10 floats
    float* Mlse = em + 327680;                        // 64*16*100
    float* Mmax = Mlse + 102400;                      // 64*16*100
    int*   lenA = (int*)(Mmax + 102400);              // 64

    int*   paths     = (int*)d_out;                   // (T,B) int32 values
    float* loss_slot = ((float*)d_out) + TT * BB;     // scalar f32

    k_emissions<<<257, 512, 0, stream>>>(words, wf, W, bias, em, lenA, loss_slot);
    k_chunk<<<1024, 128, 0, stream>>>(em, trans, lenA, Mlse, Mmax);
    k_crf<<<64, 1024, 0, stream>>>(tags, em, startv, endv, trans, lenA,
                                   Mlse, Mmax, paths, loss_slot);
}